// Round 1
// baseline (219.011 us; speedup 1.0000x reference)
//
#include <hip/hip_runtime.h>
#include <hip/hip_bf16.h>

typedef __attribute__((ext_vector_type(8))) short short8;
typedef __attribute__((ext_vector_type(4))) float f32x4;

// __float2bfloat16 emits a single HW cvt op on gfx950 (R8: bit-trick regressed).
__device__ __forceinline__ unsigned short f2bf(float f) {
  union { __hip_bfloat16 h; unsigned short u; } cv;
  cv.h = __float2bfloat16(f);
  return cv.u;
}

__device__ __forceinline__ void gld16(const void* g, void* l) {
  __builtin_amdgcn_global_load_lds(
      (const __attribute__((address_space(1))) unsigned int*)g,
      (__attribute__((address_space(3))) unsigned int*)l, 16, 0, 0);
}

__device__ __forceinline__ f32x4 mfma_bf16(short8 a, short8 b, f32x4 c) {
  return __builtin_amdgcn_mfma_f32_16x16x32_bf16(a, b, c, 0, 0, 0);
}

#define QSCALE 0.18033688011112042f  /* 0.125 * log2(e): scores in log2 domain */
#define L2E    1.4426950408889634f

// ---------------------------------------------------------------- prep ----
// One launch: blocks [0,4096) cast X fp32->bf16; blocks [4096,5120) transpose
// weights (first 768: w_attn 64-col strips; last 256: w_proj).
__global__ void prep(const float* __restrict__ x, unsigned short* __restrict__ xbf,
                     const float* __restrict__ wa, unsigned short* __restrict__ da,
                     const float* __restrict__ wp, unsigned short* __restrict__ dp) {
  __shared__ float tile[64][65];
  const int t = threadIdx.x;
  const int bid = blockIdx.x;
  if (bid < 4096) {
    int i = bid * 256 + t;
    float4 v = ((const float4*)x)[i];
    ushort4 o;
    o.x = f2bf(v.x); o.y = f2bf(v.y); o.z = f2bf(v.z); o.w = f2bf(v.w);
    ((ushort4*)xbf)[i] = o;
    return;
  }
  int idx = bid - 4096;          // 0..1023
  const int tr = idx & 15;       // 16 row-strips of 64
  int y = idx >> 4;              // 0..63
  const float* src;
  unsigned short* dst;
  int C;
  if (y < 48) { src = wa; dst = da; C = 3072; }
  else        { src = wp; dst = dp; C = 1024; y -= 48; }
  const int tc = y;  // block-uniform
#pragma unroll
  for (int i = 0; i < 16; ++i) {
    int id2 = t + i * 256;
    int lr = id2 >> 6, lc = id2 & 63;
    tile[lr][lc] = src[(size_t)(tr * 64 + lr) * C + tc * 64 + lc];
  }
  __syncthreads();
#pragma unroll
  for (int i = 0; i < 16; ++i) {
    int id2 = t + i * 256;
    int lr = id2 >> 6, lc = id2 & 63;
    dst[(size_t)(tc * 64 + lr) * 1024 + tr * 64 + lc] = f2bf(tile[lc][lr]);
  }
}

// ---------------------------------------------------------------- GEMM ----
template <int KDIM>
__device__ __forceinline__ void gemm_core(const short* __restrict__ A, const short* __restrict__ Bt,
                                          int mbase, int nbase, short* As, short* Bs,
                                          int wm, int wn, int quad, int l16, int t,
                                          f32x4 (&acc)[4][4]) {
  for (int kt = 0; kt < KDIM / 32; ++kt) {
#pragma unroll
    for (int i = 0; i < 2; ++i) {
      int c = t + i * 256;
      int row = c >> 2, c4 = c & 3;
      gld16(A + (size_t)(mbase + row) * KDIM + kt * 32 + c4 * 8, (char*)As + c * 16);
      gld16(Bt + (size_t)(nbase + row) * KDIM + kt * 32 + c4 * 8, (char*)Bs + c * 16);
    }
    __syncthreads();
    short8 af[4], bf[4];
#pragma unroll
    for (int m = 0; m < 4; ++m)
      af[m] = *(const short8*)((const char*)As + (wm + m * 16 + l16) * 64 + quad * 16);
#pragma unroll
    for (int n = 0; n < 4; ++n)
      bf[n] = *(const short8*)((const char*)Bs + (wn + n * 16 + l16) * 64 + quad * 16);
#pragma unroll
    for (int m = 0; m < 4; ++m)
#pragma unroll
      for (int n = 0; n < 4; ++n)
        acc[m][n] = mfma_bf16(af[m], bf[n], acc[m][n]);
    __syncthreads();
  }
}

// Unified QKV GEMM: grid (32, 24) = 768 blocks (3/CU). nbase<2048 -> Q/K scatter
// (Q pre-scaled by QSCALE for log2-domain flash); nbase>=2048 -> V path with
// LDS-transpose epilogue emitting V' sigma-permuted [bh][d][2048].
__global__ __launch_bounds__(256, 2) void gemm_qkv(
    const short* __restrict__ A, const short* __restrict__ Bt, const float* __restrict__ bias,
    unsigned short* __restrict__ q, unsigned short* __restrict__ k,
    unsigned short* __restrict__ vt) {
  __shared__ __align__(16) char smem[17408];
  short* As = (short*)smem;
  short* Bs = (short*)(smem + 8192);
  unsigned short* vlds = (unsigned short*)smem;  // [64 d][136] permuted s (V epilogue)
  const int t = threadIdx.x;
  const int wave = t >> 6, lane = t & 63;
  const int quad = lane >> 4, l16 = lane & 15;
  const int wm = (wave >> 1) * 64, wn = (wave & 1) * 64;
  const int mbase = blockIdx.x * 128, nbase = blockIdx.y * 128;
  f32x4 acc[4][4];
#pragma unroll
  for (int i = 0; i < 4; ++i)
#pragma unroll
    for (int j = 0; j < 4; ++j) acc[i][j] = (f32x4)0.0f;
  gemm_core<1024>(A, Bt, mbase, nbase, As, Bs, wm, wn, quad, l16, t, acc);

  if (nbase < 2048) {
    // ---- Q/K scatter epilogue ----
#pragma unroll
    for (int n = 0; n < 4; ++n) {
      int col = nbase + wn + n * 16 + l16;      // 0..2047
      float bc = bias[col];
      int which = col >> 10, rem = col & 1023;  // wave-uniform per n
      int h = rem >> 6, d = rem & 63;
      unsigned short* dst = which ? k : q;
      float scale = which ? 1.0f : QSCALE;
#pragma unroll
      for (int m = 0; m < 4; ++m) {
#pragma unroll
        for (int r = 0; r < 4; ++r) {
          int row = mbase + wm + m * 16 + quad * 4 + r;
          int b = row >> 11, s = row & 2047;
          dst[(((size_t)(b * 16 + h)) * 2048 + s) * 64 + d] = f2bf((acc[m][n][r] + bc) * scale);
        }
      }
    }
  } else {
    // ---- V transpose epilogue: V'[bh][d][kt*128 + sigma(s)], sigma(s)=(s&15)*8+(s>>4)
    const int b = mbase >> 11, s0 = mbase & 2047;
    const int vcb = nbase - 2048;  // 0..895, v-column base
    __syncthreads();               // hard fence before vlds reuses the GEMM stage region
#pragma unroll
    for (int half = 0; half < 2; ++half) {
      if (wn == half * 64) {
#pragma unroll
        for (int n = 0; n < 4; ++n) {
          int col_l = n * 16 + l16;  // d 0..63
          float bc = bias[nbase + half * 64 + col_l];
#pragma unroll
          for (int m = 0; m < 4; ++m)
#pragma unroll
            for (int r = 0; r < 4; ++r) {
              int row_l = wm + m * 16 + quad * 4 + r;  // s_local 0..127
              vlds[col_l * 136 + ((row_l & 15) * 8 + (row_l >> 4))] = f2bf(acc[m][n][r] + bc);
            }
        }
      }
      __syncthreads();
      int h = (vcb + half * 64) >> 6;  // head 0..15
      size_t obase = ((size_t)(b * 16 + h)) * 64 * 2048;
#pragma unroll
      for (int i = 0; i < 4; ++i) {
        int c = t + i * 256;
        int d_l = c >> 4, c16 = c & 15;
        short8 v = *(const short8*)&vlds[d_l * 136 + c16 * 8];
        *(short8*)&vt[obase + (size_t)d_l * 2048 + s0 + c16 * 8] = v;
      }
      __syncthreads();
    }
  }
}

// Proj: 64x128 tiles, grid (64,8) = 512 blocks (2/CU) — R8-proven correct+faster.
__global__ __launch_bounds__(256, 2) void gemm_proj(
    const short* __restrict__ A, const short* __restrict__ Bt, const float* __restrict__ bias,
    float* __restrict__ out) {
  __shared__ __align__(16) short As[64 * 32];
  __shared__ __align__(16) short Bs[128 * 32];
  const int t = threadIdx.x;
  const int wave = t >> 6, lane = t & 63;
  const int quad = lane >> 4, l16 = lane & 15;
  const int wm = (wave >> 1) * 32, wn = (wave & 1) * 64;
  const int mbase = blockIdx.x * 64, nbase = blockIdx.y * 128;
  f32x4 acc[2][4];
#pragma unroll
  for (int i = 0; i < 2; ++i)
#pragma unroll
    for (int j = 0; j < 4; ++j) acc[i][j] = (f32x4)0.0f;
  for (int kt = 0; kt < 32; ++kt) {
    {  // A: 64 rows x 4 chunks = 256 chunks, 1/thread
      int row = t >> 2, c4 = t & 3;
      gld16(A + (size_t)(mbase + row) * 1024 + kt * 32 + c4 * 8, (char*)As + t * 16);
    }
#pragma unroll
    for (int i = 0; i < 2; ++i) {  // B: 128 rows x 4 chunks = 512 chunks, 2/thread
      int c = t + i * 256;
      int row = c >> 2, c4 = c & 3;
      gld16(Bt + (size_t)(nbase + row) * 1024 + kt * 32 + c4 * 8, (char*)Bs + c * 16);
    }
    __syncthreads();
    short8 af[2], bf[4];
#pragma unroll
    for (int m = 0; m < 2; ++m)
      af[m] = *(const short8*)((const char*)As + (wm + m * 16 + l16) * 64 + quad * 16);
#pragma unroll
    for (int n = 0; n < 4; ++n)
      bf[n] = *(const short8*)((const char*)Bs + (wn + n * 16 + l16) * 64 + quad * 16);
#pragma unroll
    for (int m = 0; m < 2; ++m)
#pragma unroll
      for (int n = 0; n < 4; ++n)
        acc[m][n] = mfma_bf16(af[m], bf[n], acc[m][n]);
    __syncthreads();
  }
#pragma unroll
  for (int n = 0; n < 4; ++n) {
    int col = nbase + wn + n * 16 + l16;
    float bc = bias[col];
#pragma unroll
    for (int m = 0; m < 2; ++m)
#pragma unroll
      for (int r = 0; r < 4; ++r) {
        int row = mbase + wm + m * 16 + quad * 4 + r;
        out[(size_t)row * 1024 + col] = acc[m][n][r] + bc;
      }
  }
}

// ---------------------------------------------------------------- flash ----
// Br=64 per 128-thread block (2 waves x 32 q-rows). Grid (32 bh, 32 qt).
// R11: latency-bound fix (was MfmaUtil 21 / VALUBusy 34 / 45% idle at the hard
// 2-wave/SIMD occupancy cap).
//  * K double-buffered (2 x 16K) with stage-ahead: gld16 for kt+1 issued BEFORE
//    compute(kt), single barrier/kt -> the vmcnt(0) drain at the barrier lands
//    after ~600cy of compute instead of stalling cold (T3 minimum-2-phase).
//  * V never touches LDS: V' is sigma-permuted [bh][d][2048], so each lane's
//    PV B-fragment is ONE contiguous 16B global load (L2-resident: round-robin
//    grid puts all 32 qt-blocks of a bh on one XCD, 4 bh x 512KB = 2MB < L2).
//    Issue order mask -> vfc -> stage so in-order vmcnt lets softmax wait only
//    on mask and PV only on vfc while stage loads stay in flight.
//  * LDS = 2*16384 (K dbuf) + 8192 (P) = 40960 EXACTLY -> 4 blocks/CU
//    (R10: 50176 -> 2 blocks/CU cliff).
//  * T5 setprio(1) around QK/PV MFMA clusters (pays once stage-ahead creates
//    wave role-diversity; m191 +4-7%).
// P rows wave-private so only a compiler fence (R10-proven) orders write->read.
__global__ __launch_bounds__(128, 2) void flash_attn(
    const short* __restrict__ Qg, const short* __restrict__ Kg, const short* __restrict__ Vtg,
    const float* __restrict__ mask, unsigned short* __restrict__ ctx) {
  __shared__ __align__(16) unsigned char smem[40960];
  short* Psm = (short*)(smem + 32768);   // [32 rows][16 chunks] swizzled, m-half
  const int t = threadIdx.x;  // 0..127
  const int wave = t >> 6, lane = t & 63;
  const int quad = lane >> 4, l16 = lane & 15;
  const int bh = blockIdx.x, b = bh >> 4, h = bh & 15;
  const int qbase = blockIdx.y * 64;
  const size_t bh_off = (size_t)bh * 2048 * 64;

  // ---- Q stage into Kbuf0 region, then to registers ----
#pragma unroll
  for (int i = 0; i < 4; ++i) {
    int c = t + i * 128;
    int row = c >> 3, col = c & 7;
    gld16(Qg + bh_off + (size_t)(qbase + row) * 64 + (col ^ (row & 7)) * 8,
          (char*)smem + c * 16);
  }
  __syncthreads();
  short8 qf[2][2];
#pragma unroll
  for (int m = 0; m < 2; ++m)
#pragma unroll
    for (int ks = 0; ks < 2; ++ks) {
      int row = wave * 32 + m * 16 + l16;
      qf[m][ks] = *(const short8*)((const char*)smem +
                                   (row * 8 + ((ks * 4 + quad) ^ (l16 & 7))) * 16);
    }
  __syncthreads();  // all waves done reading Q before K staging reuses region

  auto stage_k = [&](char* dst, int kn) {
#pragma unroll
    for (int i = 0; i < 8; ++i) {
      int c = t + i * 128;
      int row = c >> 3, col = c & 7;
      gld16(Kg + bh_off + (size_t)(kn * 128 + row) * 64 + (col ^ (row & 7)) * 8,
            dst + c * 16);
    }
  };

  f32x4 O[2][4];
  float l_i[2][4];
#pragma unroll
  for (int m = 0; m < 2; ++m)
#pragma unroll
    for (int d = 0; d < 4; ++d) O[m][d] = (f32x4)0.0f;
#pragma unroll
  for (int m = 0; m < 2; ++m)
#pragma unroll
    for (int r = 0; r < 4; ++r) l_i[m][r] = 0.0f;

  // prologue: stage kt=0 into buf0 (only cold stall of the kernel)
  stage_k((char*)smem, 0);
  __syncthreads();

  for (int kt = 0; kt < 16; ++kt) {
    const char* Kc = (const char*)smem + (kt & 1) * 16384;
    char* Kn = (char*)smem + ((kt + 1) & 1) * 16384;

    // mask first (consumed first, softmax m=0)
    float mv[8];
#pragma unroll
    for (int n = 0; n < 8; ++n) mv[n] = mask[b * 2048 + kt * 128 + n * 16 + l16];

    // V fragments straight from global (sigma-permuted layout makes each lane's
    // 8 k-elements contiguous): consumed at PV, after softmax
    short8 vfc[4][4];
#pragma unroll
    for (int ks = 0; ks < 4; ++ks)
#pragma unroll
      for (int db = 0; db < 4; ++db)
        vfc[ks][db] = *(const short8*)(Vtg + ((size_t)bh * 64 + db * 16 + l16) * 2048 +
                                       kt * 128 + (ks * 4 + quad) * 8);

    // stage-ahead: K tile for kt+1 (newest in vmcnt queue; drained at barrier)
    if (kt < 15) stage_k(Kn, kt + 1);

    // ---- S = Q @ K^T (log2 domain), both m-tiles per kf read ----
    f32x4 sa[2][8];
#pragma unroll
    for (int m = 0; m < 2; ++m)
#pragma unroll
      for (int n = 0; n < 8; ++n) sa[m][n] = (f32x4)0.0f;
    __builtin_amdgcn_s_setprio(1);
#pragma unroll
    for (int ks = 0; ks < 2; ++ks) {
#pragma unroll
      for (int n = 0; n < 8; ++n) {
        int row = n * 16 + l16;
        short8 kf = *(const short8*)(Kc + (row * 8 + ((ks * 4 + quad) ^ (l16 & 7))) * 16);
        sa[0][n] = mfma_bf16(qf[0][ks], kf, sa[0][n]);
        sa[1][n] = mfma_bf16(qf[1][ks], kf, sa[1][n]);
      }
    }
    __builtin_amdgcn_s_setprio(0);

#pragma unroll
    for (int m = 0; m < 2; ++m) {
      // softmax m-half -> P (one b128/row, XOR-swizzled stride-256 layout)
#pragma unroll
      for (int r = 0; r < 4; ++r) {
        float rs = 0.0f;
        short8 p8;
#pragma unroll
        for (int n = 0; n < 8; ++n) {
          float p = __builtin_amdgcn_exp2f(__builtin_fmaf(mv[n], L2E, sa[m][n][r]));
          rs += p;
          p8[n] = (short)f2bf(p);
        }
        int prow = wave * 16 + quad * 4 + r;  // 0..31, wave-private half
        *(short8*)((char*)Psm + prow * 256 + ((l16 ^ (prow & 7)) * 16)) = p8;
        l_i[m][r] += rs;
      }
      // compiler-only fence: P rows wave-private, HW DS per-wave in-order (R10-proven)
      asm volatile("" ::: "memory");

      // O[m] += P @ V'
      __builtin_amdgcn_s_setprio(1);
#pragma unroll
      for (int ks = 0; ks < 4; ++ks) {
        int prow = wave * 16 + l16;
        short8 pf = *(const short8*)((const char*)Psm +
                                     prow * 256 + (((ks * 4 + quad) ^ (l16 & 7)) * 16));
#pragma unroll
        for (int db = 0; db < 4; ++db)
          O[m][db] = mfma_bf16(pf, vfc[ks][db], O[m][db]);
      }
      __builtin_amdgcn_s_setprio(0);
      // fence: m=1 P-writes must not hoist above m=0 P-reads
      asm volatile("" ::: "memory");
    }
    // one barrier/kt: K reads of buf[cur] done block-wide + next stage drained
    __syncthreads();
  }

#pragma unroll
  for (int m = 0; m < 2; ++m) {
#pragma unroll
    for (int r = 0; r < 4; ++r) {
      float l = l_i[m][r];
      l += __shfl_xor(l, 1);
      l += __shfl_xor(l, 2);
      l += __shfl_xor(l, 4);
      l += __shfl_xor(l, 8);
      float inv = 1.0f / l;
      int s = qbase + wave * 32 + m * 16 + quad * 4 + r;
      size_t o = ((size_t)b * 2048 + s) * 1024 + h * 64;
#pragma unroll
      for (int db = 0; db < 4; ++db)
        ctx[o + db * 16 + l16] = f2bf(O[m][db][r] * inv);
    }
  }
}

// ---------------------------------------------------------------- launch ----
extern "C" void kernel_launch(void* const* d_in, const int* in_sizes, int n_in,
                              void* d_out, int out_size, void* d_ws, size_t ws_size,
                              hipStream_t stream) {
  const float* x      = (const float*)d_in[0];
  const float* mask   = (const float*)d_in[1];
  const float* w_attn = (const float*)d_in[2];
  const float* b_attn = (const float*)d_in[3];
  const float* w_proj = (const float*)d_in[4];
  const float* b_proj = (const float*)d_in[5];
  float* out = (float*)d_out;

  char* ws = (char*)d_ws;
  const size_t MB = 1024 * 1024;
  short*          Xbf    = (short*)(ws);                     // 8 MB, reused as ctx
  short*          Wqkv_t = (short*)(ws + 8 * MB);            // 6 MB
  short*          Wprj_t = (short*)(ws + 14 * MB);           // 2 MB
  unsigned short* Qb     = (unsigned short*)(ws + 16 * MB);  // 8 MB
  unsigned short* Kb     = (unsigned short*)(ws + 24 * MB);  // 8 MB
  unsigned short* Vtb    = (unsigned short*)(ws + 32 * MB);  // 8 MB
  unsigned short* ctx    = (unsigned short*)Xbf;

  prep<<<5120, 256, 0, stream>>>(x, (unsigned short*)Xbf,
                                 w_attn, (unsigned short*)Wqkv_t,
                                 w_proj, (unsigned short*)Wprj_t);
  gemm_qkv<<<dim3(32, 24), 256, 0, stream>>>(Xbf, Wqkv_t, b_attn, Qb, Kb, Vtb);
  flash_attn<<<dim3(32, 32), 128, 0, stream>>>((const short*)Qb, (const short*)Kb,
                                               (const short*)Vtb, mask, ctx);
  gemm_proj<<<dim3(64, 8), 256, 0, stream>>>((const short*)ctx, Wprj_t, b_proj, out);
}

// Round 2
// 188.665 us; speedup vs baseline: 1.1608x; 1.1608x over previous
//
#include <hip/hip_runtime.h>
#include <hip/hip_bf16.h>

typedef __attribute__((ext_vector_type(8))) short short8;
typedef __attribute__((ext_vector_type(4))) short short4v;
typedef __attribute__((ext_vector_type(4))) float f32x4;

// __float2bfloat16 emits a single HW cvt op on gfx950 (R8: bit-trick regressed).
__device__ __forceinline__ unsigned short f2bf(float f) {
  union { __hip_bfloat16 h; unsigned short u; } cv;
  cv.h = __float2bfloat16(f);
  return cv.u;
}

__device__ __forceinline__ void gld16(const void* g, void* l) {
  __builtin_amdgcn_global_load_lds(
      (const __attribute__((address_space(1))) unsigned int*)g,
      (__attribute__((address_space(3))) unsigned int*)l, 16, 0, 0);
}

__device__ __forceinline__ f32x4 mfma_bf16(short8 a, short8 b, f32x4 c) {
  return __builtin_amdgcn_mfma_f32_16x16x32_bf16(a, b, c, 0, 0, 0);
}

#define QSCALE 0.18033688011112042f  /* 0.125 * log2(e): scores in log2 domain */
#define L2E    1.4426950408889634f

// ---------------------------------------------------------------- prep ----
// One launch: blocks [0,4096) cast X fp32->bf16; blocks [4096,5120) transpose
// weights (first 768: w_attn 64-col strips; last 256: w_proj).
__global__ void prep(const float* __restrict__ x, unsigned short* __restrict__ xbf,
                     const float* __restrict__ wa, unsigned short* __restrict__ da,
                     const float* __restrict__ wp, unsigned short* __restrict__ dp) {
  __shared__ float tile[64][65];
  const int t = threadIdx.x;
  const int bid = blockIdx.x;
  if (bid < 4096) {
    int i = bid * 256 + t;
    float4 v = ((const float4*)x)[i];
    ushort4 o;
    o.x = f2bf(v.x); o.y = f2bf(v.y); o.z = f2bf(v.z); o.w = f2bf(v.w);
    ((ushort4*)xbf)[i] = o;
    return;
  }
  int idx = bid - 4096;          // 0..1023
  const int tr = idx & 15;       // 16 row-strips of 64
  int y = idx >> 4;              // 0..63
  const float* src;
  unsigned short* dst;
  int C;
  if (y < 48) { src = wa; dst = da; C = 3072; }
  else        { src = wp; dst = dp; C = 1024; y -= 48; }
  const int tc = y;  // block-uniform
#pragma unroll
  for (int i = 0; i < 16; ++i) {
    int id2 = t + i * 256;
    int lr = id2 >> 6, lc = id2 & 63;
    tile[lr][lc] = src[(size_t)(tr * 64 + lr) * C + tc * 64 + lc];
  }
  __syncthreads();
#pragma unroll
  for (int i = 0; i < 16; ++i) {
    int id2 = t + i * 256;
    int lr = id2 >> 6, lc = id2 & 63;
    dst[(size_t)(tc * 64 + lr) * 1024 + tr * 64 + lc] = f2bf(tile[lc][lr]);
  }
}

// ---------------------------------------------------------------- GEMM ----
template <int KDIM>
__device__ __forceinline__ void gemm_core(const short* __restrict__ A, const short* __restrict__ Bt,
                                          int mbase, int nbase, short* As, short* Bs,
                                          int wm, int wn, int quad, int l16, int t,
                                          f32x4 (&acc)[4][4]) {
  for (int kt = 0; kt < KDIM / 32; ++kt) {
#pragma unroll
    for (int i = 0; i < 2; ++i) {
      int c = t + i * 256;
      int row = c >> 2, c4 = c & 3;
      gld16(A + (size_t)(mbase + row) * KDIM + kt * 32 + c4 * 8, (char*)As + c * 16);
      gld16(Bt + (size_t)(nbase + row) * KDIM + kt * 32 + c4 * 8, (char*)Bs + c * 16);
    }
    __syncthreads();
    short8 af[4], bf[4];
#pragma unroll
    for (int m = 0; m < 4; ++m)
      af[m] = *(const short8*)((const char*)As + (wm + m * 16 + l16) * 64 + quad * 16);
#pragma unroll
    for (int n = 0; n < 4; ++n)
      bf[n] = *(const short8*)((const char*)Bs + (wn + n * 16 + l16) * 64 + quad * 16);
#pragma unroll
    for (int m = 0; m < 4; ++m)
#pragma unroll
      for (int n = 0; n < 4; ++n)
        acc[m][n] = mfma_bf16(af[m], bf[n], acc[m][n]);
    __syncthreads();
  }
}

// Unified QKV GEMM: grid (32, 24) = 768 blocks (3/CU). nbase<2048 -> Q/K scatter
// (Q pre-scaled by QSCALE for log2-domain flash); nbase>=2048 -> V path with
// LDS-transpose epilogue emitting V' sigma64-permuted [bh][d][2048]:
// stored pos (per 64-block) = (s&15)*4 + (s>>4)  [matches flash P layout].
__global__ __launch_bounds__(256, 2) void gemm_qkv(
    const short* __restrict__ A, const short* __restrict__ Bt, const float* __restrict__ bias,
    unsigned short* __restrict__ q, unsigned short* __restrict__ k,
    unsigned short* __restrict__ vt) {
  __shared__ __align__(16) char smem[17408];
  short* As = (short*)smem;
  short* Bs = (short*)(smem + 8192);
  unsigned short* vlds = (unsigned short*)smem;  // [64 d][136] permuted s (V epilogue)
  const int t = threadIdx.x;
  const int wave = t >> 6, lane = t & 63;
  const int quad = lane >> 4, l16 = lane & 15;
  const int wm = (wave >> 1) * 64, wn = (wave & 1) * 64;
  const int mbase = blockIdx.x * 128, nbase = blockIdx.y * 128;
  f32x4 acc[4][4];
#pragma unroll
  for (int i = 0; i < 4; ++i)
#pragma unroll
    for (int j = 0; j < 4; ++j) acc[i][j] = (f32x4)0.0f;
  gemm_core<1024>(A, Bt, mbase, nbase, As, Bs, wm, wn, quad, l16, t, acc);

  if (nbase < 2048) {
    // ---- Q/K scatter epilogue ----
#pragma unroll
    for (int n = 0; n < 4; ++n) {
      int col = nbase + wn + n * 16 + l16;      // 0..2047
      float bc = bias[col];
      int which = col >> 10, rem = col & 1023;  // wave-uniform per n
      int h = rem >> 6, d = rem & 63;
      unsigned short* dst = which ? k : q;
      float scale = which ? 1.0f : QSCALE;
#pragma unroll
      for (int m = 0; m < 4; ++m) {
#pragma unroll
        for (int r = 0; r < 4; ++r) {
          int row = mbase + wm + m * 16 + quad * 4 + r;
          int b = row >> 11, s = row & 2047;
          dst[(((size_t)(b * 16 + h)) * 2048 + s) * 64 + d] = f2bf((acc[m][n][r] + bc) * scale);
        }
      }
    }
  } else {
    // ---- V transpose epilogue: sigma64 per 64-block:
    // idx = (row_l & 64) + (row_l&15)*4 + ((row_l>>4)&3)
    const int b = mbase >> 11, s0 = mbase & 2047;
    const int vcb = nbase - 2048;  // 0..895, v-column base
    __syncthreads();               // hard fence before vlds reuses the GEMM stage region
#pragma unroll
    for (int half = 0; half < 2; ++half) {
      if (wn == half * 64) {
#pragma unroll
        for (int n = 0; n < 4; ++n) {
          int col_l = n * 16 + l16;  // d 0..63
          float bc = bias[nbase + half * 64 + col_l];
#pragma unroll
          for (int m = 0; m < 4; ++m)
#pragma unroll
            for (int r = 0; r < 4; ++r) {
              int row_l = wm + m * 16 + quad * 4 + r;  // s_local 0..127
              int idx = (row_l & 64) + (row_l & 15) * 4 + ((row_l >> 4) & 3);
              vlds[col_l * 136 + idx] = f2bf(acc[m][n][r] + bc);
            }
        }
      }
      __syncthreads();
      int h = (vcb + half * 64) >> 6;  // head 0..15
      size_t obase = ((size_t)(b * 16 + h)) * 64 * 2048;
#pragma unroll
      for (int i = 0; i < 4; ++i) {
        int c = t + i * 256;
        int d_l = c >> 4, c16 = c & 15;
        short8 v = *(const short8*)&vlds[d_l * 136 + c16 * 8];
        *(short8*)&vt[obase + (size_t)d_l * 2048 + s0 + c16 * 8] = v;
      }
      __syncthreads();
    }
  }
}

// Proj: 64x128 tiles, grid (64,8) = 512 blocks (2/CU) — R8-proven correct+faster.
__global__ __launch_bounds__(256, 2) void gemm_proj(
    const short* __restrict__ A, const short* __restrict__ Bt, const float* __restrict__ bias,
    float* __restrict__ out) {
  __shared__ __align__(16) short As[64 * 32];
  __shared__ __align__(16) short Bs[128 * 32];
  const int t = threadIdx.x;
  const int wave = t >> 6, lane = t & 63;
  const int quad = lane >> 4, l16 = lane & 15;
  const int wm = (wave >> 1) * 32, wn = (wave & 1) * 64;
  const int mbase = blockIdx.x * 64, nbase = blockIdx.y * 128;
  f32x4 acc[2][4];
#pragma unroll
  for (int i = 0; i < 2; ++i)
#pragma unroll
    for (int j = 0; j < 4; ++j) acc[i][j] = (f32x4)0.0f;
  for (int kt = 0; kt < 32; ++kt) {
    {  // A: 64 rows x 4 chunks = 256 chunks, 1/thread
      int row = t >> 2, c4 = t & 3;
      gld16(A + (size_t)(mbase + row) * 1024 + kt * 32 + c4 * 8, (char*)As + t * 16);
    }
#pragma unroll
    for (int i = 0; i < 2; ++i) {  // B: 128 rows x 4 chunks = 512 chunks, 2/thread
      int c = t + i * 256;
      int row = c >> 2, c4 = c & 3;
      gld16(Bt + (size_t)(nbase + row) * 1024 + kt * 32 + c4 * 8, (char*)Bs + c * 16);
    }
    __syncthreads();
    short8 af[2], bf[4];
#pragma unroll
    for (int m = 0; m < 2; ++m)
      af[m] = *(const short8*)((const char*)As + (wm + m * 16 + l16) * 64 + quad * 16);
#pragma unroll
    for (int n = 0; n < 4; ++n)
      bf[n] = *(const short8*)((const char*)Bs + (wn + n * 16 + l16) * 64 + quad * 16);
#pragma unroll
    for (int m = 0; m < 2; ++m)
#pragma unroll
      for (int n = 0; n < 4; ++n)
        acc[m][n] = mfma_bf16(af[m], bf[n], acc[m][n]);
    __syncthreads();
  }
#pragma unroll
  for (int n = 0; n < 4; ++n) {
    int col = nbase + wn + n * 16 + l16;
    float bc = bias[col];
#pragma unroll
    for (int m = 0; m < 2; ++m)
#pragma unroll
      for (int r = 0; r < 4; ++r) {
        int row = mbase + wm + m * 16 + quad * 4 + r;
        out[(size_t)row * 1024 + col] = acc[m][n][r] + bc;
      }
  }
}

// ---------------------------------------------------------------- flash ----
// R12: KVBLK=64, 256-thread blocks (4 waves x 16 q-rows), Br=64, grid (32,32).
// Fixes R11's regression (uncoalesced per-lane V gathers) while keeping its
// pipelining, AND doubles TLP:
//  * LDS = K dbuf 2x8K + V dbuf 2x8K + P 8K = 40960 EXACTLY -> 4 blocks/CU
//    -> 16 waves/CU = 4 waves/SIMD (2x round-0's TLP; latency-bound fix).
//  * Both K and V double-buffered, staged with coalesced gld16; stage(kt+1)
//    issued BEFORE compute(kt); ONE barrier/kt (drain lands after compute).
//  * V' sigma64-permuted so LDS V rows are [d][8 chunks], XOR-swizzled; PV
//    B-frags are single b128 LDS reads (conflict-free by uniform spread).
//  * P: [64 q][64 s] stored in sigma64 order; 8B writes (4-way = bank floor),
//    16B reads swizzled conflict-free. Rows wave-private -> compiler fence
//    only (R10-proven pattern).
//  * T5 setprio(1) around QK/PV MFMA clusters.
__global__ __launch_bounds__(256, 4) void flash_attn(
    const short* __restrict__ Qg, const short* __restrict__ Kg, const short* __restrict__ Vtg,
    const float* __restrict__ mask, unsigned short* __restrict__ ctx) {
  __shared__ __align__(16) unsigned char smem[40960];
  // K: [0,16384) two 8K buffers; V: [16384,32768) two 8K buffers; P: [32768,40960)
  short* Psm = (short*)(smem + 32768);
  const int t = threadIdx.x;  // 0..255
  const int wave = t >> 6, lane = t & 63;
  const int quad = lane >> 4, l16 = lane & 15;
  const int bh = blockIdx.x, b = bh >> 4, h = bh & 15;
  const int qbase = blockIdx.y * 64;
  const size_t bh_off = (size_t)bh * 2048 * 64;

  // ---- Q stage into Kbuf0 region, then to registers ----
#pragma unroll
  for (int i = 0; i < 2; ++i) {
    int c = t + i * 256;
    int row = c >> 3, col = c & 7;
    gld16(Qg + bh_off + (size_t)(qbase + row) * 64 + (col ^ (row & 7)) * 8,
          (char*)smem + c * 16);
  }
  __syncthreads();
  short8 qf[2];
#pragma unroll
  for (int ks = 0; ks < 2; ++ks) {
    int row = wave * 16 + l16;
    qf[ks] = *(const short8*)((const char*)smem +
                              (row * 8 + ((ks * 4 + quad) ^ (l16 & 7))) * 16);
  }
  __syncthreads();  // all waves done reading Q before K staging reuses region

  auto stage = [&](int kn) {
    char* kd = (char*)smem + (kn & 1) * 8192;
    char* vd = (char*)smem + 16384 + (kn & 1) * 8192;
#pragma unroll
    for (int i = 0; i < 2; ++i) {
      int c = t + i * 256;
      int row = c >> 3, col = c & 7;  // row: K s-row / V d-row; col: 8-chunk
      gld16(Kg + bh_off + (size_t)(kn * 64 + row) * 64 + (col ^ (row & 7)) * 8,
            kd + c * 16);
      gld16(Vtg + ((size_t)bh * 64 + row) * 2048 + kn * 64 + (col ^ (row & 7)) * 8,
            vd + c * 16);
    }
  };

  f32x4 O[4];
  float l_i[4];
#pragma unroll
  for (int d = 0; d < 4; ++d) O[d] = (f32x4)0.0f;
#pragma unroll
  for (int r = 0; r < 4; ++r) l_i[r] = 0.0f;

  // prologue: stage kt=0 into buf0 (only cold stall of the kernel)
  stage(0);
  __syncthreads();

  for (int kt = 0; kt < 32; ++kt) {
    const char* Kc = (const char*)smem + (kt & 1) * 8192;
    const char* Vc = (const char*)smem + 16384 + (kt & 1) * 8192;

    float mv[4];
#pragma unroll
    for (int n = 0; n < 4; ++n) mv[n] = mask[b * 2048 + kt * 64 + n * 16 + l16];

    // stage-ahead: K/V tiles for kt+1 (drained at the end-of-iter barrier,
    // after a full compute phase)
    if (kt < 31) stage(kt + 1);

    // ---- S = Q @ K^T (log2 domain) ----
    f32x4 sa[4];
#pragma unroll
    for (int n = 0; n < 4; ++n) sa[n] = (f32x4)0.0f;
    __builtin_amdgcn_s_setprio(1);
#pragma unroll
    for (int ks = 0; ks < 2; ++ks) {
#pragma unroll
      for (int n = 0; n < 4; ++n) {
        int row = n * 16 + l16;
        short8 kf = *(const short8*)(Kc + (row * 8 + ((ks * 4 + quad) ^ (l16 & 7))) * 16);
        sa[n] = mfma_bf16(qf[ks], kf, sa[n]);
      }
    }
    __builtin_amdgcn_s_setprio(0);

    // ---- softmax -> P (sigma64 stored order; 8B write per row) ----
#pragma unroll
    for (int r = 0; r < 4; ++r) {
      float rs = 0.0f;
      short4v p4;
#pragma unroll
      for (int n = 0; n < 4; ++n) {
        float p = __builtin_amdgcn_exp2f(__builtin_fmaf(mv[n], L2E, sa[n][r]));
        rs += p;
        p4[n] = (short)f2bf(p);
      }
      int prow = wave * 16 + quad * 4 + r;  // wave-private row
      // lane's 4 values = stored cols [l16*4, l16*4+4) = logical 8B-chunk l16;
      // 16B-chunk (l16>>1) XOR-swizzled by row, 8B half l16&1.
      *(short4v*)((char*)Psm + prow * 128 +
                  (((l16 >> 1) ^ (prow & 7)) * 16) + (l16 & 1) * 8) = p4;
      l_i[r] += rs;
    }
    // compiler-only fence: P rows wave-private, HW DS per-wave in-order (R10-proven)
    asm volatile("" ::: "memory");

    // ---- O += P @ V' ----
    __builtin_amdgcn_s_setprio(1);
#pragma unroll
    for (int ks = 0; ks < 2; ++ks) {
      int u = ks * 4 + quad;  // stored 16B-chunk 0..7
      int prow = wave * 16 + l16;
      short8 pf = *(const short8*)((const char*)Psm + prow * 128 + ((u ^ (l16 & 7)) * 16));
#pragma unroll
      for (int db = 0; db < 4; ++db) {
        int d = db * 16 + l16;
        short8 vf = *(const short8*)(Vc + d * 128 + ((u ^ (d & 7)) * 16));
        O[db] = mfma_bf16(pf, vf, O[db]);
      }
    }
    __builtin_amdgcn_s_setprio(0);

    // one barrier/kt: buf[cur] reads done block-wide + kt+1 stage drained
    __syncthreads();
  }

#pragma unroll
  for (int r = 0; r < 4; ++r) {
    float l = l_i[r];
    l += __shfl_xor(l, 1);
    l += __shfl_xor(l, 2);
    l += __shfl_xor(l, 4);
    l += __shfl_xor(l, 8);
    float inv = 1.0f / l;
    int s = qbase + wave * 16 + quad * 4 + r;
    size_t o = ((size_t)b * 2048 + s) * 1024 + h * 64;
#pragma unroll
    for (int db = 0; db < 4; ++db)
      ctx[o + db * 16 + l16] = f2bf(O[db][r] * inv);
  }
}

// ---------------------------------------------------------------- launch ----
extern "C" void kernel_launch(void* const* d_in, const int* in_sizes, int n_in,
                              void* d_out, int out_size, void* d_ws, size_t ws_size,
                              hipStream_t stream) {
  const float* x      = (const float*)d_in[0];
  const float* mask   = (const float*)d_in[1];
  const float* w_attn = (const float*)d_in[2];
  const float* b_attn = (const float*)d_in[3];
  const float* w_proj = (const float*)d_in[4];
  const float* b_proj = (const float*)d_in[5];
  float* out = (float*)d_out;

  char* ws = (char*)d_ws;
  const size_t MB = 1024 * 1024;
  short*          Xbf    = (short*)(ws);                     // 8 MB, reused as ctx
  short*          Wqkv_t = (short*)(ws + 8 * MB);            // 6 MB
  short*          Wprj_t = (short*)(ws + 14 * MB);           // 2 MB
  unsigned short* Qb     = (unsigned short*)(ws + 16 * MB);  // 8 MB
  unsigned short* Kb     = (unsigned short*)(ws + 24 * MB);  // 8 MB
  unsigned short* Vtb    = (unsigned short*)(ws + 32 * MB);  // 8 MB
  unsigned short* ctx    = (unsigned short*)Xbf;

  prep<<<5120, 256, 0, stream>>>(x, (unsigned short*)Xbf,
                                 w_attn, (unsigned short*)Wqkv_t,
                                 w_proj, (unsigned short*)Wprj_t);
  gemm_qkv<<<dim3(32, 24), 256, 0, stream>>>(Xbf, Wqkv_t, b_attn, Qb, Kb, Vtb);
  flash_attn<<<dim3(32, 32), 256, 0, stream>>>((const short*)Qb, (const short*)Kb,
                                               (const short*)Vtb, mask, ctx);
  gemm_proj<<<dim3(64, 8), 256, 0, stream>>>((const short*)ctx, Wprj_t, b_proj, out);
}

// Round 3
// 184.515 us; speedup vs baseline: 1.1870x; 1.0225x over previous
//
#include <hip/hip_runtime.h>
#include <hip/hip_bf16.h>

typedef __attribute__((ext_vector_type(8))) short short8;
typedef __attribute__((ext_vector_type(4))) short short4v;
typedef __attribute__((ext_vector_type(4))) float f32x4;

// __float2bfloat16 emits a single HW cvt op on gfx950 (R8: bit-trick regressed).
__device__ __forceinline__ unsigned short f2bf(float f) {
  union { __hip_bfloat16 h; unsigned short u; } cv;
  cv.h = __float2bfloat16(f);
  return cv.u;
}

__device__ __forceinline__ void gld16(const void* g, void* l) {
  __builtin_amdgcn_global_load_lds(
      (const __attribute__((address_space(1))) unsigned int*)g,
      (__attribute__((address_space(3))) unsigned int*)l, 16, 0, 0);
}

__device__ __forceinline__ f32x4 mfma_bf16(short8 a, short8 b, f32x4 c) {
  return __builtin_amdgcn_mfma_f32_16x16x32_bf16(a, b, c, 0, 0, 0);
}

#define QSCALE 0.18033688011112042f  /* 0.125 * log2(e): scores in log2 domain */
#define L2E    1.4426950408889634f

// ---------------------------------------------------------------- prep ----
// One launch: blocks [0,4096) cast X fp32->bf16; blocks [4096,5120) transpose
// weights (first 768: w_attn 64-col strips; last 256: w_proj).
__global__ void prep(const float* __restrict__ x, unsigned short* __restrict__ xbf,
                     const float* __restrict__ wa, unsigned short* __restrict__ da,
                     const float* __restrict__ wp, unsigned short* __restrict__ dp) {
  __shared__ float tile[64][65];
  const int t = threadIdx.x;
  const int bid = blockIdx.x;
  if (bid < 4096) {
    int i = bid * 256 + t;
    float4 v = ((const float4*)x)[i];
    ushort4 o;
    o.x = f2bf(v.x); o.y = f2bf(v.y); o.z = f2bf(v.z); o.w = f2bf(v.w);
    ((ushort4*)xbf)[i] = o;
    return;
  }
  int idx = bid - 4096;          // 0..1023
  const int tr = idx & 15;       // 16 row-strips of 64
  int y = idx >> 4;              // 0..63
  const float* src;
  unsigned short* dst;
  int C;
  if (y < 48) { src = wa; dst = da; C = 3072; }
  else        { src = wp; dst = dp; C = 1024; y -= 48; }
  const int tc = y;  // block-uniform
#pragma unroll
  for (int i = 0; i < 16; ++i) {
    int id2 = t + i * 256;
    int lr = id2 >> 6, lc = id2 & 63;
    tile[lr][lc] = src[(size_t)(tr * 64 + lr) * C + tc * 64 + lc];
  }
  __syncthreads();
#pragma unroll
  for (int i = 0; i < 16; ++i) {
    int id2 = t + i * 256;
    int lr = id2 >> 6, lc = id2 & 63;
    dst[(size_t)(tc * 64 + lr) * 1024 + tr * 64 + lc] = f2bf(tile[lc][lr]);
  }
}

// ---------------------------------------------------------------- GEMM ----
template <int KDIM>
__device__ __forceinline__ void gemm_core(const short* __restrict__ A, const short* __restrict__ Bt,
                                          int mbase, int nbase, short* As, short* Bs,
                                          int wm, int wn, int quad, int l16, int t,
                                          f32x4 (&acc)[4][4]) {
  for (int kt = 0; kt < KDIM / 32; ++kt) {
#pragma unroll
    for (int i = 0; i < 2; ++i) {
      int c = t + i * 256;
      int row = c >> 2, c4 = c & 3;
      gld16(A + (size_t)(mbase + row) * KDIM + kt * 32 + c4 * 8, (char*)As + c * 16);
      gld16(Bt + (size_t)(nbase + row) * KDIM + kt * 32 + c4 * 8, (char*)Bs + c * 16);
    }
    __syncthreads();
    short8 af[4], bf[4];
#pragma unroll
    for (int m = 0; m < 4; ++m)
      af[m] = *(const short8*)((const char*)As + (wm + m * 16 + l16) * 64 + quad * 16);
#pragma unroll
    for (int n = 0; n < 4; ++n)
      bf[n] = *(const short8*)((const char*)Bs + (wn + n * 16 + l16) * 64 + quad * 16);
#pragma unroll
    for (int m = 0; m < 4; ++m)
#pragma unroll
      for (int n = 0; n < 4; ++n)
        acc[m][n] = mfma_bf16(af[m], bf[n], acc[m][n]);
    __syncthreads();
  }
}

// Unified QKV GEMM: grid (32, 24) = 768 blocks (3/CU). nbase<2048 -> Q/K scatter
// (Q pre-scaled by QSCALE for log2-domain flash); nbase>=2048 -> V path with
// LDS-transpose epilogue emitting V' sigma64-permuted [bh][d][2048]:
// stored pos (per 64-block) = (s&15)*4 + (s>>4)  [matches flash P layout].
__global__ __launch_bounds__(256, 2) void gemm_qkv(
    const short* __restrict__ A, const short* __restrict__ Bt, const float* __restrict__ bias,
    unsigned short* __restrict__ q, unsigned short* __restrict__ k,
    unsigned short* __restrict__ vt) {
  __shared__ __align__(16) char smem[17408];
  short* As = (short*)smem;
  short* Bs = (short*)(smem + 8192);
  unsigned short* vlds = (unsigned short*)smem;  // [64 d][136] permuted s (V epilogue)
  const int t = threadIdx.x;
  const int wave = t >> 6, lane = t & 63;
  const int quad = lane >> 4, l16 = lane & 15;
  const int wm = (wave >> 1) * 64, wn = (wave & 1) * 64;
  const int mbase = blockIdx.x * 128, nbase = blockIdx.y * 128;
  f32x4 acc[4][4];
#pragma unroll
  for (int i = 0; i < 4; ++i)
#pragma unroll
    for (int j = 0; j < 4; ++j) acc[i][j] = (f32x4)0.0f;
  gemm_core<1024>(A, Bt, mbase, nbase, As, Bs, wm, wn, quad, l16, t, acc);

  if (nbase < 2048) {
    // ---- Q/K scatter epilogue ----
#pragma unroll
    for (int n = 0; n < 4; ++n) {
      int col = nbase + wn + n * 16 + l16;      // 0..2047
      float bc = bias[col];
      int which = col >> 10, rem = col & 1023;  // wave-uniform per n
      int h = rem >> 6, d = rem & 63;
      unsigned short* dst = which ? k : q;
      float scale = which ? 1.0f : QSCALE;
#pragma unroll
      for (int m = 0; m < 4; ++m) {
#pragma unroll
        for (int r = 0; r < 4; ++r) {
          int row = mbase + wm + m * 16 + quad * 4 + r;
          int b = row >> 11, s = row & 2047;
          dst[(((size_t)(b * 16 + h)) * 2048 + s) * 64 + d] = f2bf((acc[m][n][r] + bc) * scale);
        }
      }
    }
  } else {
    // ---- V transpose epilogue: sigma64 per 64-block:
    // idx = (row_l & 64) + (row_l&15)*4 + ((row_l>>4)&3)
    const int b = mbase >> 11, s0 = mbase & 2047;
    const int vcb = nbase - 2048;  // 0..895, v-column base
    __syncthreads();               // hard fence before vlds reuses the GEMM stage region
#pragma unroll
    for (int half = 0; half < 2; ++half) {
      if (wn == half * 64) {
#pragma unroll
        for (int n = 0; n < 4; ++n) {
          int col_l = n * 16 + l16;  // d 0..63
          float bc = bias[nbase + half * 64 + col_l];
#pragma unroll
          for (int m = 0; m < 4; ++m)
#pragma unroll
            for (int r = 0; r < 4; ++r) {
              int row_l = wm + m * 16 + quad * 4 + r;  // s_local 0..127
              int idx = (row_l & 64) + (row_l & 15) * 4 + ((row_l >> 4) & 3);
              vlds[col_l * 136 + idx] = f2bf(acc[m][n][r] + bc);
            }
        }
      }
      __syncthreads();
      int h = (vcb + half * 64) >> 6;  // head 0..15
      size_t obase = ((size_t)(b * 16 + h)) * 64 * 2048;
#pragma unroll
      for (int i = 0; i < 4; ++i) {
        int c = t + i * 256;
        int d_l = c >> 4, c16 = c & 15;
        short8 v = *(const short8*)&vlds[d_l * 136 + c16 * 8];
        *(short8*)&vt[obase + (size_t)d_l * 2048 + s0 + c16 * 8] = v;
      }
      __syncthreads();
    }
  }
}

// Proj: 64x128 tiles, grid (64,8) = 512 blocks (2/CU) — R8-proven correct+faster.
__global__ __launch_bounds__(256, 2) void gemm_proj(
    const short* __restrict__ A, const short* __restrict__ Bt, const float* __restrict__ bias,
    float* __restrict__ out) {
  __shared__ __align__(16) short As[64 * 32];
  __shared__ __align__(16) short Bs[128 * 32];
  const int t = threadIdx.x;
  const int wave = t >> 6, lane = t & 63;
  const int quad = lane >> 4, l16 = lane & 15;
  const int wm = (wave >> 1) * 32, wn = (wave & 1) * 64;
  const int mbase = blockIdx.x * 64, nbase = blockIdx.y * 128;
  f32x4 acc[2][4];
#pragma unroll
  for (int i = 0; i < 2; ++i)
#pragma unroll
    for (int j = 0; j < 4; ++j) acc[i][j] = (f32x4)0.0f;
  for (int kt = 0; kt < 32; ++kt) {
    {  // A: 64 rows x 4 chunks = 256 chunks, 1/thread
      int row = t >> 2, c4 = t & 3;
      gld16(A + (size_t)(mbase + row) * 1024 + kt * 32 + c4 * 8, (char*)As + t * 16);
    }
#pragma unroll
    for (int i = 0; i < 2; ++i) {  // B: 128 rows x 4 chunks = 512 chunks, 2/thread
      int c = t + i * 256;
      int row = c >> 2, c4 = c & 3;
      gld16(Bt + (size_t)(nbase + row) * 1024 + kt * 32 + c4 * 8, (char*)Bs + c * 16);
    }
    __syncthreads();
    short8 af[2], bf[4];
#pragma unroll
    for (int m = 0; m < 2; ++m)
      af[m] = *(const short8*)((const char*)As + (wm + m * 16 + l16) * 64 + quad * 16);
#pragma unroll
    for (int n = 0; n < 4; ++n)
      bf[n] = *(const short8*)((const char*)Bs + (wn + n * 16 + l16) * 64 + quad * 16);
#pragma unroll
    for (int m = 0; m < 2; ++m)
#pragma unroll
      for (int n = 0; n < 4; ++n)
        acc[m][n] = mfma_bf16(af[m], bf[n], acc[m][n]);
    __syncthreads();
  }
#pragma unroll
  for (int n = 0; n < 4; ++n) {
    int col = nbase + wn + n * 16 + l16;
    float bc = bias[col];
#pragma unroll
    for (int m = 0; m < 2; ++m)
#pragma unroll
      for (int r = 0; r < 4; ++r) {
        int row = mbase + wm + m * 16 + quad * 4 + r;
        out[(size_t)row * 1024 + col] = acc[m][n][r] + bc;
      }
  }
}

// ---------------------------------------------------------------- flash ----
// R13: Br=128, 256 threads (4 waves x 32 q-rows = 2 M-frags/wave), KVBLK=64,
// grid (32 bh, 16 qt) = 512 blocks = 2/CU.
// R12 post-mortem: LDS read pipe was the wall (18 b128/wave-kt for 16 MFMAs
// ~= 34 us of bank time at 128 B/cy; occupancy doubling bought only 7%).
// Fix = fragment REUSE, not TLP: each kf feeds 2 MFMAs (sa[0],sa[1]), each vf
// feeds 2 (O[0],O[1]). 20 reads / 32 MFMAs -> bytes/MAC down 1.55x; per-CU
// LDS floor ~20.5 us vs MFMA floor ~16.5 us (balanced).
//  * LDS = K dbuf 2x8K + V dbuf 2x8K + P 16K = 49152 (3 blocks/CU cap; grid
//    gives 2 -> irrelevant).
//  * Same R12 stage-ahead single-barrier pipeline, same zero-conflict
//    swizzles, same sigma64 V'/P layouts. Longer compute phase per kt hides
//    the barrier drain better at 2 waves/SIMD.
//  * Dispatch x-major: all qt-blocks of a bh land on one XCD (bh%8) -> K/V
//    re-stages are L2 hits (4 bh x 512 KB = 2 MB < 4 MB L2/XCD).
__global__ __launch_bounds__(256, 2) void flash_attn(
    const short* __restrict__ Qg, const short* __restrict__ Kg, const short* __restrict__ Vtg,
    const float* __restrict__ mask, unsigned short* __restrict__ ctx) {
  __shared__ __align__(16) unsigned char smem[49152];
  // K: [0,16384) two 8K buffers; V: [16384,32768) two 8K buffers; P: [32768,49152)
  short* Psm = (short*)(smem + 32768);  // [128 q][64 s] swizzled rows of 128 B
  const int t = threadIdx.x;  // 0..255
  const int wave = t >> 6, lane = t & 63;
  const int quad = lane >> 4, l16 = lane & 15;
  const int bh = blockIdx.x, b = bh >> 4, h = bh & 15;
  const int qbase = blockIdx.y * 128;
  const size_t bh_off = (size_t)bh * 2048 * 64;

  // ---- Q stage (16 KB = K-dbuf region), then to registers ----
#pragma unroll
  for (int i = 0; i < 4; ++i) {
    int c = t + i * 256;
    int row = c >> 3, col = c & 7;
    gld16(Qg + bh_off + (size_t)(qbase + row) * 64 + (col ^ (row & 7)) * 8,
          (char*)smem + c * 16);
  }
  __syncthreads();
  short8 qf[2][2];  // [m-frag][ks]
#pragma unroll
  for (int mf = 0; mf < 2; ++mf)
#pragma unroll
    for (int ks = 0; ks < 2; ++ks) {
      int row = wave * 32 + mf * 16 + l16;
      qf[mf][ks] = *(const short8*)((const char*)smem +
                                    (row * 8 + ((ks * 4 + quad) ^ (l16 & 7))) * 16);
    }
  __syncthreads();  // all waves done reading Q before K staging reuses region

  auto stage = [&](int kn) {
    char* kd = (char*)smem + (kn & 1) * 8192;
    char* vd = (char*)smem + 16384 + (kn & 1) * 8192;
#pragma unroll
    for (int i = 0; i < 2; ++i) {
      int c = t + i * 256;
      int row = c >> 3, col = c & 7;  // row: K s-row / V d-row; col: 8-chunk
      gld16(Kg + bh_off + (size_t)(kn * 64 + row) * 64 + (col ^ (row & 7)) * 8,
            kd + c * 16);
      gld16(Vtg + ((size_t)bh * 64 + row) * 2048 + kn * 64 + (col ^ (row & 7)) * 8,
            vd + c * 16);
    }
  };

  f32x4 O[2][4];
  float l_i[2][4];
#pragma unroll
  for (int mf = 0; mf < 2; ++mf)
#pragma unroll
    for (int d = 0; d < 4; ++d) O[mf][d] = (f32x4)0.0f;
#pragma unroll
  for (int mf = 0; mf < 2; ++mf)
#pragma unroll
    for (int r = 0; r < 4; ++r) l_i[mf][r] = 0.0f;

  // prologue: stage kt=0 into buf0 (only cold stall of the kernel)
  stage(0);
  __syncthreads();

  for (int kt = 0; kt < 32; ++kt) {
    const char* Kc = (const char*)smem + (kt & 1) * 8192;
    const char* Vc = (const char*)smem + 16384 + (kt & 1) * 8192;

    float mv[4];
#pragma unroll
    for (int n = 0; n < 4; ++n) mv[n] = mask[b * 2048 + kt * 64 + n * 16 + l16];

    // stage-ahead: K/V tiles for kt+1 (drained at the end-of-iter barrier,
    // after a full compute phase)
    if (kt < 31) stage(kt + 1);

    // ---- S = Q @ K^T (log2 domain); each kf feeds BOTH m-frags ----
    f32x4 sa[2][4];
#pragma unroll
    for (int mf = 0; mf < 2; ++mf)
#pragma unroll
      for (int n = 0; n < 4; ++n) sa[mf][n] = (f32x4)0.0f;
    __builtin_amdgcn_s_setprio(1);
#pragma unroll
    for (int ks = 0; ks < 2; ++ks) {
#pragma unroll
      for (int n = 0; n < 4; ++n) {
        int row = n * 16 + l16;
        short8 kf = *(const short8*)(Kc + (row * 8 + ((ks * 4 + quad) ^ (l16 & 7))) * 16);
        sa[0][n] = mfma_bf16(qf[0][ks], kf, sa[0][n]);
        sa[1][n] = mfma_bf16(qf[1][ks], kf, sa[1][n]);
      }
    }
    __builtin_amdgcn_s_setprio(0);

    // ---- softmax -> P (sigma64 stored order; 8B write per row), both m-frags ----
#pragma unroll
    for (int mf = 0; mf < 2; ++mf) {
#pragma unroll
      for (int r = 0; r < 4; ++r) {
        float rs = 0.0f;
        short4v p4;
#pragma unroll
        for (int n = 0; n < 4; ++n) {
          float p = __builtin_amdgcn_exp2f(__builtin_fmaf(mv[n], L2E, sa[mf][n][r]));
          rs += p;
          p4[n] = (short)f2bf(p);
        }
        int prow = wave * 32 + mf * 16 + quad * 4 + r;  // wave-private row
        *(short4v*)((char*)Psm + prow * 128 +
                    (((l16 >> 1) ^ (prow & 7)) * 16) + (l16 & 1) * 8) = p4;
        l_i[mf][r] += rs;
      }
    }
    // compiler-only fence: P rows wave-private, HW DS per-wave in-order (R10-proven)
    asm volatile("" ::: "memory");

    // ---- O += P @ V'; each vf feeds BOTH m-frags ----
    __builtin_amdgcn_s_setprio(1);
#pragma unroll
    for (int ks = 0; ks < 2; ++ks) {
      int u = ks * 4 + quad;  // stored 16B-chunk 0..7
      short8 vf[4];
#pragma unroll
      for (int db = 0; db < 4; ++db) {
        int d = db * 16 + l16;
        vf[db] = *(const short8*)(Vc + d * 128 + ((u ^ (d & 7)) * 16));
      }
#pragma unroll
      for (int mf = 0; mf < 2; ++mf) {
        int prow = wave * 32 + mf * 16 + l16;
        short8 pf = *(const short8*)((const char*)Psm + prow * 128 + ((u ^ (l16 & 7)) * 16));
#pragma unroll
        for (int db = 0; db < 4; ++db)
          O[mf][db] = mfma_bf16(pf, vf[db], O[mf][db]);
      }
    }
    __builtin_amdgcn_s_setprio(0);

    // one barrier/kt: buf[cur] reads done block-wide + kt+1 stage drained
    __syncthreads();
  }

#pragma unroll
  for (int mf = 0; mf < 2; ++mf) {
#pragma unroll
    for (int r = 0; r < 4; ++r) {
      float l = l_i[mf][r];
      l += __shfl_xor(l, 1);
      l += __shfl_xor(l, 2);
      l += __shfl_xor(l, 4);
      l += __shfl_xor(l, 8);
      float inv = 1.0f / l;
      int s = qbase + wave * 32 + mf * 16 + quad * 4 + r;
      size_t o = ((size_t)b * 2048 + s) * 1024 + h * 64;
#pragma unroll
      for (int db = 0; db < 4; ++db)
        ctx[o + db * 16 + l16] = f2bf(O[mf][db][r] * inv);
    }
  }
}

// ---------------------------------------------------------------- launch ----
extern "C" void kernel_launch(void* const* d_in, const int* in_sizes, int n_in,
                              void* d_out, int out_size, void* d_ws, size_t ws_size,
                              hipStream_t stream) {
  const float* x      = (const float*)d_in[0];
  const float* mask   = (const float*)d_in[1];
  const float* w_attn = (const float*)d_in[2];
  const float* b_attn = (const float*)d_in[3];
  const float* w_proj = (const float*)d_in[4];
  const float* b_proj = (const float*)d_in[5];
  float* out = (float*)d_out;

  char* ws = (char*)d_ws;
  const size_t MB = 1024 * 1024;
  short*          Xbf    = (short*)(ws);                     // 8 MB, reused as ctx
  short*          Wqkv_t = (short*)(ws + 8 * MB);            // 6 MB
  short*          Wprj_t = (short*)(ws + 14 * MB);           // 2 MB
  unsigned short* Qb     = (unsigned short*)(ws + 16 * MB);  // 8 MB
  unsigned short* Kb     = (unsigned short*)(ws + 24 * MB);  // 8 MB
  unsigned short* Vtb    = (unsigned short*)(ws + 32 * MB);  // 8 MB
  unsigned short* ctx    = (unsigned short*)Xbf;

  prep<<<5120, 256, 0, stream>>>(x, (unsigned short*)Xbf,
                                 w_attn, (unsigned short*)Wqkv_t,
                                 w_proj, (unsigned short*)Wprj_t);
  gemm_qkv<<<dim3(32, 24), 256, 0, stream>>>(Xbf, Wqkv_t, b_attn, Qb, Kb, Vtb);
  flash_attn<<<dim3(32, 16), 256, 0, stream>>>((const short*)Qb, (const short*)Kb,
                                               (const short*)Vtb, mask, ctx);
  gemm_proj<<<dim3(64, 8), 256, 0, stream>>>((const short*)ctx, Wprj_t, b_proj, out);
}

// Round 4
// 177.410 us; speedup vs baseline: 1.2345x; 1.0400x over previous
//
#include <hip/hip_runtime.h>
#include <hip/hip_bf16.h>

typedef __attribute__((ext_vector_type(8))) short short8;
typedef __attribute__((ext_vector_type(4))) float f32x4;

// __float2bfloat16 emits a single HW cvt op on gfx950 (R8: bit-trick regressed).
__device__ __forceinline__ unsigned short f2bf(float f) {
  union { __hip_bfloat16 h; unsigned short u; } cv;
  cv.h = __float2bfloat16(f);
  return cv.u;
}

__device__ __forceinline__ void gld16(const void* g, void* l) {
  __builtin_amdgcn_global_load_lds(
      (const __attribute__((address_space(1))) unsigned int*)g,
      (__attribute__((address_space(3))) unsigned int*)l, 16, 0, 0);
}

__device__ __forceinline__ f32x4 mfma_bf16(short8 a, short8 b, f32x4 c) {
  return __builtin_amdgcn_mfma_f32_16x16x32_bf16(a, b, c, 0, 0, 0);
}

#define QSCALE 0.18033688011112042f  /* 0.125 * log2(e): scores in log2 domain */
#define L2E    1.4426950408889634f

// ---------------------------------------------------------------- prep ----
// One launch: blocks [0,4096) cast X fp32->bf16; blocks [4096,5120) transpose
// weights (first 768: w_attn 64-col strips; last 256: w_proj).
__global__ void prep(const float* __restrict__ x, unsigned short* __restrict__ xbf,
                     const float* __restrict__ wa, unsigned short* __restrict__ da,
                     const float* __restrict__ wp, unsigned short* __restrict__ dp) {
  __shared__ float tile[64][65];
  const int t = threadIdx.x;
  const int bid = blockIdx.x;
  if (bid < 4096) {
    int i = bid * 256 + t;
    float4 v = ((const float4*)x)[i];
    ushort4 o;
    o.x = f2bf(v.x); o.y = f2bf(v.y); o.z = f2bf(v.z); o.w = f2bf(v.w);
    ((ushort4*)xbf)[i] = o;
    return;
  }
  int idx = bid - 4096;          // 0..1023
  const int tr = idx & 15;       // 16 row-strips of 64
  int y = idx >> 4;              // 0..63
  const float* src;
  unsigned short* dst;
  int C;
  if (y < 48) { src = wa; dst = da; C = 3072; }
  else        { src = wp; dst = dp; C = 1024; y -= 48; }
  const int tc = y;  // block-uniform
#pragma unroll
  for (int i = 0; i < 16; ++i) {
    int id2 = t + i * 256;
    int lr = id2 >> 6, lc = id2 & 63;
    tile[lr][lc] = src[(size_t)(tr * 64 + lr) * C + tc * 64 + lc];
  }
  __syncthreads();
#pragma unroll
  for (int i = 0; i < 16; ++i) {
    int id2 = t + i * 256;
    int lr = id2 >> 6, lc = id2 & 63;
    dst[(size_t)(tc * 64 + lr) * 1024 + tr * 64 + lc] = f2bf(tile[lc][lr]);
  }
}

// ---------------------------------------------------------------- GEMM ----
template <int KDIM>
__device__ __forceinline__ void gemm_core(const short* __restrict__ A, const short* __restrict__ Bt,
                                          int mbase, int nbase, short* As, short* Bs,
                                          int wm, int wn, int quad, int l16, int t,
                                          f32x4 (&acc)[4][4]) {
  for (int kt = 0; kt < KDIM / 32; ++kt) {
#pragma unroll
    for (int i = 0; i < 2; ++i) {
      int c = t + i * 256;
      int row = c >> 2, c4 = c & 3;
      gld16(A + (size_t)(mbase + row) * KDIM + kt * 32 + c4 * 8, (char*)As + c * 16);
      gld16(Bt + (size_t)(nbase + row) * KDIM + kt * 32 + c4 * 8, (char*)Bs + c * 16);
    }
    __syncthreads();
    short8 af[4], bf[4];
#pragma unroll
    for (int m = 0; m < 4; ++m)
      af[m] = *(const short8*)((const char*)As + (wm + m * 16 + l16) * 64 + quad * 16);
#pragma unroll
    for (int n = 0; n < 4; ++n)
      bf[n] = *(const short8*)((const char*)Bs + (wn + n * 16 + l16) * 64 + quad * 16);
#pragma unroll
    for (int m = 0; m < 4; ++m)
#pragma unroll
      for (int n = 0; n < 4; ++n)
        acc[m][n] = mfma_bf16(af[m], bf[n], acc[m][n]);
    __syncthreads();
  }
}

// Unified QKV GEMM: grid (32, 24) = 768 blocks (3/CU). nbase<2048 -> Q/K scatter
// (Q pre-scaled by QSCALE for log2-domain flash); nbase>=2048 -> V path with
// LDS-transpose epilogue emitting V' tau64-permuted [bh][d][2048]:
// stored pos (per 64-block) = 32*s5 + 8*((s>>2)&3) + 4*s4 + (s&3).
// tau64 matches flash's in-register P packing (swapped-QK S^T frags pack
// in-lane into PV A-operands with NO cross-lane moves).
__global__ __launch_bounds__(256, 2) void gemm_qkv(
    const short* __restrict__ A, const short* __restrict__ Bt, const float* __restrict__ bias,
    unsigned short* __restrict__ q, unsigned short* __restrict__ k,
    unsigned short* __restrict__ vt) {
  __shared__ __align__(16) char smem[17408];
  short* As = (short*)smem;
  short* Bs = (short*)(smem + 8192);
  unsigned short* vlds = (unsigned short*)smem;  // [64 d][136] permuted s (V epilogue)
  const int t = threadIdx.x;
  const int wave = t >> 6, lane = t & 63;
  const int quad = lane >> 4, l16 = lane & 15;
  const int wm = (wave >> 1) * 64, wn = (wave & 1) * 64;
  const int mbase = blockIdx.x * 128, nbase = blockIdx.y * 128;
  f32x4 acc[4][4];
#pragma unroll
  for (int i = 0; i < 4; ++i)
#pragma unroll
    for (int j = 0; j < 4; ++j) acc[i][j] = (f32x4)0.0f;
  gemm_core<1024>(A, Bt, mbase, nbase, As, Bs, wm, wn, quad, l16, t, acc);

  if (nbase < 2048) {
    // ---- Q/K scatter epilogue ----
#pragma unroll
    for (int n = 0; n < 4; ++n) {
      int col = nbase + wn + n * 16 + l16;      // 0..2047
      float bc = bias[col];
      int which = col >> 10, rem = col & 1023;  // wave-uniform per n
      int h = rem >> 6, d = rem & 63;
      unsigned short* dst = which ? k : q;
      float scale = which ? 1.0f : QSCALE;
#pragma unroll
      for (int m = 0; m < 4; ++m) {
#pragma unroll
        for (int r = 0; r < 4; ++r) {
          int row = mbase + wm + m * 16 + quad * 4 + r;
          int b = row >> 11, s = row & 2047;
          dst[(((size_t)(b * 16 + h)) * 2048 + s) * 64 + d] = f2bf((acc[m][n][r] + bc) * scale);
        }
      }
    }
  } else {
    // ---- V transpose epilogue: tau64 per 64-block ----
    const int b = mbase >> 11, s0 = mbase & 2047;
    const int vcb = nbase - 2048;  // 0..895, v-column base
    __syncthreads();               // hard fence before vlds reuses the GEMM stage region
#pragma unroll
    for (int half = 0; half < 2; ++half) {
      if (wn == half * 64) {
#pragma unroll
        for (int n = 0; n < 4; ++n) {
          int col_l = n * 16 + l16;  // d 0..63
          float bc = bias[nbase + half * 64 + col_l];
#pragma unroll
          for (int m = 0; m < 4; ++m)
#pragma unroll
            for (int r = 0; r < 4; ++r) {
              int row_l = wm + m * 16 + quad * 4 + r;  // s_local 0..127
              int idx = (row_l & 64) + ((row_l >> 5) & 1) * 32 +
                        ((row_l >> 2) & 3) * 8 + ((row_l >> 4) & 1) * 4 + (row_l & 3);
              vlds[col_l * 136 + idx] = f2bf(acc[m][n][r] + bc);
            }
        }
      }
      __syncthreads();
      int h = (vcb + half * 64) >> 6;  // head 0..15
      size_t obase = ((size_t)(b * 16 + h)) * 64 * 2048;
#pragma unroll
      for (int i = 0; i < 4; ++i) {
        int c = t + i * 256;
        int d_l = c >> 4, c16 = c & 15;
        short8 v = *(const short8*)&vlds[d_l * 136 + c16 * 8];
        *(short8*)&vt[obase + (size_t)d_l * 2048 + s0 + c16 * 8] = v;
      }
      __syncthreads();
    }
  }
}

// Proj: 64x128 tiles, grid (64,8) = 512 blocks (2/CU) — R8-proven correct+faster.
__global__ __launch_bounds__(256, 2) void gemm_proj(
    const short* __restrict__ A, const short* __restrict__ Bt, const float* __restrict__ bias,
    float* __restrict__ out) {
  __shared__ __align__(16) short As[64 * 32];
  __shared__ __align__(16) short Bs[128 * 32];
  const int t = threadIdx.x;
  const int wave = t >> 6, lane = t & 63;
  const int quad = lane >> 4, l16 = lane & 15;
  const int wm = (wave >> 1) * 32, wn = (wave & 1) * 64;
  const int mbase = blockIdx.x * 64, nbase = blockIdx.y * 128;
  f32x4 acc[2][4];
#pragma unroll
  for (int i = 0; i < 2; ++i)
#pragma unroll
    for (int j = 0; j < 4; ++j) acc[i][j] = (f32x4)0.0f;
  for (int kt = 0; kt < 32; ++kt) {
    {  // A: 64 rows x 4 chunks = 256 chunks, 1/thread
      int row = t >> 2, c4 = t & 3;
      gld16(A + (size_t)(mbase + row) * 1024 + kt * 32 + c4 * 8, (char*)As + t * 16);
    }
#pragma unroll
    for (int i = 0; i < 2; ++i) {  // B: 128 rows x 4 chunks = 512 chunks, 2/thread
      int c = t + i * 256;
      int row = c >> 2, c4 = c & 3;
      gld16(Bt + (size_t)(nbase + row) * 1024 + kt * 32 + c4 * 8, (char*)Bs + c * 16);
    }
    __syncthreads();
    short8 af[2], bf[4];
#pragma unroll
    for (int m = 0; m < 2; ++m)
      af[m] = *(const short8*)((const char*)As + (wm + m * 16 + l16) * 64 + quad * 16);
#pragma unroll
    for (int n = 0; n < 4; ++n)
      bf[n] = *(const short8*)((const char*)Bs + (wn + n * 16 + l16) * 64 + quad * 16);
#pragma unroll
    for (int m = 0; m < 2; ++m)
#pragma unroll
      for (int n = 0; n < 4; ++n)
        acc[m][n] = mfma_bf16(af[m], bf[n], acc[m][n]);
    __syncthreads();
  }
#pragma unroll
  for (int n = 0; n < 4; ++n) {
    int col = nbase + wn + n * 16 + l16;
    float bc = bias[col];
#pragma unroll
    for (int m = 0; m < 2; ++m)
#pragma unroll
      for (int r = 0; r < 4; ++r) {
        int row = mbase + wm + m * 16 + quad * 4 + r;
        out[(size_t)row * 1024 + col] = acc[m][n][r] + bc;
      }
  }
}

// ---------------------------------------------------------------- flash ----
// R14: swapped-QK in-register softmax — P never touches LDS.
// Br=128, 256 threads (4 waves x 32 q = 2 m-frags), KVBLK=64, grid (32,16).
// R13 post-mortem: LDS pipe floor ~34 us (20 b128 reads + 8 P-writes/wave-kt
// at 85 B/cy), measured 53 us, MFMA already at its 13.7 us floor. 12 of the 20
// reads + all writes were the P round-trip.
// Fix: S^T = mfma(A=kf, B=qf) (operand reads UNCHANGED in form) -> lane holds
// q=l16, k=quad*4+reg per n-frag. With V' stored in tau64 order
// (p = 32*s5 + 8*((s>>2)&3) + 4*s4 + (s&3)), each lane's own S^T values pack
// IN-LANE, IN-ORDER into the PV A-fragments: softmax->PV is pure register
// dataflow (no LDS, no fences, no cross-lane). LDS/wave-kt: 320 -> 224 cy
// (floor ~24 us). mask loaded as float4 per n-frag (indexed quad*4+r).
// l_i: per-lane partials (q=l16), one quad-reduce + shfl transpose at end.
// LDS = K dbuf 2x8K + V dbuf 2x8K = 32768. Same stage-ahead 1-barrier/kt.
__global__ __launch_bounds__(256, 2) void flash_attn(
    const short* __restrict__ Qg, const short* __restrict__ Kg, const short* __restrict__ Vtg,
    const float* __restrict__ mask, unsigned short* __restrict__ ctx) {
  __shared__ __align__(16) unsigned char smem[32768];
  // K: [0,16384) two 8K buffers; V: [16384,32768) two 8K buffers
  const int t = threadIdx.x;  // 0..255
  const int wave = t >> 6, lane = t & 63;
  const int quad = lane >> 4, l16 = lane & 15;
  const int bh = blockIdx.x, b = bh >> 4, h = bh & 15;
  const int qbase = blockIdx.y * 128;
  const size_t bh_off = (size_t)bh * 2048 * 64;

  // ---- Q stage (16 KB = K-dbuf region), then to registers ----
#pragma unroll
  for (int i = 0; i < 4; ++i) {
    int c = t + i * 256;
    int row = c >> 3, col = c & 7;
    gld16(Qg + bh_off + (size_t)(qbase + row) * 64 + (col ^ (row & 7)) * 8,
          (char*)smem + c * 16);
  }
  __syncthreads();
  short8 qf[2][2];  // [m-frag][ks]
#pragma unroll
  for (int mf = 0; mf < 2; ++mf)
#pragma unroll
    for (int ks = 0; ks < 2; ++ks) {
      int row = wave * 32 + mf * 16 + l16;
      qf[mf][ks] = *(const short8*)((const char*)smem +
                                    (row * 8 + ((ks * 4 + quad) ^ (l16 & 7))) * 16);
    }
  __syncthreads();  // all waves done reading Q before K staging reuses region

  auto stage = [&](int kn) {
    char* kd = (char*)smem + (kn & 1) * 8192;
    char* vd = (char*)smem + 16384 + (kn & 1) * 8192;
#pragma unroll
    for (int i = 0; i < 2; ++i) {
      int c = t + i * 256;
      int row = c >> 3, col = c & 7;  // row: K s-row / V d-row; col: 8-chunk
      gld16(Kg + bh_off + (size_t)(kn * 64 + row) * 64 + (col ^ (row & 7)) * 8,
            kd + c * 16);
      gld16(Vtg + ((size_t)bh * 64 + row) * 2048 + kn * 64 + (col ^ (row & 7)) * 8,
            vd + c * 16);
    }
  };

  f32x4 O[2][4];
  float l_part[2];
#pragma unroll
  for (int mf = 0; mf < 2; ++mf)
#pragma unroll
    for (int d = 0; d < 4; ++d) O[mf][d] = (f32x4)0.0f;
  l_part[0] = 0.0f;
  l_part[1] = 0.0f;

  // prologue: stage kt=0 into buf0 (only cold stall of the kernel)
  stage(0);
  __syncthreads();

  for (int kt = 0; kt < 32; ++kt) {
    const char* Kc = (const char*)smem + (kt & 1) * 8192;
    const char* Vc = (const char*)smem + 16384 + (kt & 1) * 8192;

    // mask: float4 per n-frag at s = kt*64 + n*16 + quad*4 (16B aligned)
    float4 mq[4];
#pragma unroll
    for (int n = 0; n < 4; ++n)
      mq[n] = *(const float4*)&mask[b * 2048 + kt * 64 + n * 16 + quad * 4];

    // stage-ahead: K/V tiles for kt+1 (drained at the end-of-iter barrier)
    if (kt < 31) stage(kt + 1);

    // ---- S^T = K @ Q^T (log2 domain); kf feeds BOTH m-frags ----
    f32x4 sa[2][4];
#pragma unroll
    for (int mf = 0; mf < 2; ++mf)
#pragma unroll
      for (int n = 0; n < 4; ++n) sa[mf][n] = (f32x4)0.0f;
    __builtin_amdgcn_s_setprio(1);
#pragma unroll
    for (int ks = 0; ks < 2; ++ks) {
#pragma unroll
      for (int n = 0; n < 4; ++n) {
        int row = n * 16 + l16;
        short8 kf = *(const short8*)(Kc + (row * 8 + ((ks * 4 + quad) ^ (l16 & 7))) * 16);
        sa[0][n] = mfma_bf16(kf, qf[0][ks], sa[0][n]);
        sa[1][n] = mfma_bf16(kf, qf[1][ks], sa[1][n]);
      }
    }
    __builtin_amdgcn_s_setprio(0);

    // ---- softmax fully in-register: lane owns q=l16, k = n*16+quad*4+r ----
    // Pack straight into PV A-frags: pa[mf][ks] elems = frag(2ks) r0..3,
    // frag(2ks+1) r0..3  (= contraction positions ks*32+quad*8+{0..7} = tau64)
    short8 pa[2][2];
#pragma unroll
    for (int mf = 0; mf < 2; ++mf) {
      float rs = 0.0f;
#pragma unroll
      for (int n = 0; n < 4; ++n) {
#pragma unroll
        for (int r = 0; r < 4; ++r) {
          float p = __builtin_amdgcn_exp2f(__builtin_fmaf(mq[n][r], L2E, sa[mf][n][r]));
          rs += p;
          pa[mf][n >> 1][(n & 1) * 4 + r] = (short)f2bf(p);
        }
      }
      l_part[mf] += rs;
    }

    // ---- O += P @ V' (vf feeds BOTH m-frags) ----
    __builtin_amdgcn_s_setprio(1);
#pragma unroll
    for (int ks = 0; ks < 2; ++ks) {
      int u = ks * 4 + quad;  // stored 16B-chunk 0..7
#pragma unroll
      for (int db = 0; db < 4; ++db) {
        int d = db * 16 + l16;
        short8 vf = *(const short8*)(Vc + d * 128 + ((u ^ (d & 7)) * 16));
        O[0][db] = mfma_bf16(pa[0][ks], vf, O[0][db]);
        O[1][db] = mfma_bf16(pa[1][ks], vf, O[1][db]);
      }
    }
    __builtin_amdgcn_s_setprio(0);

    // one barrier/kt: buf[cur] reads done block-wide + kt+1 stage drained
    __syncthreads();
  }

  // ---- l reduce: sum over quads (lane bits 4,5), then transpose to O layout ----
  float lr[2];
#pragma unroll
  for (int mf = 0; mf < 2; ++mf) {
    float l = l_part[mf];
    l += __shfl_xor(l, 16);
    l += __shfl_xor(l, 32);
    lr[mf] = l;  // valid for q = l16 (all quads hold it)
  }
#pragma unroll
  for (int mf = 0; mf < 2; ++mf) {
#pragma unroll
    for (int r = 0; r < 4; ++r) {
      float lq = __shfl(lr[mf], quad * 4 + r);  // l for q-local = quad*4+r
      float inv = 1.0f / lq;
      int s = qbase + wave * 32 + mf * 16 + quad * 4 + r;
      size_t o = ((size_t)b * 2048 + s) * 1024 + h * 64;
#pragma unroll
      for (int db = 0; db < 4; ++db)
        ctx[o + db * 16 + l16] = f2bf(O[mf][db][r] * inv);
    }
  }
}

// ---------------------------------------------------------------- launch ----
extern "C" void kernel_launch(void* const* d_in, const int* in_sizes, int n_in,
                              void* d_out, int out_size, void* d_ws, size_t ws_size,
                              hipStream_t stream) {
  const float* x      = (const float*)d_in[0];
  const float* mask   = (const float*)d_in[1];
  const float* w_attn = (const float*)d_in[2];
  const float* b_attn = (const float*)d_in[3];
  const float* w_proj = (const float*)d_in[4];
  const float* b_proj = (const float*)d_in[5];
  float* out = (float*)d_out;

  char* ws = (char*)d_ws;
  const size_t MB = 1024 * 1024;
  short*          Xbf    = (short*)(ws);                     // 8 MB, reused as ctx
  short*          Wqkv_t = (short*)(ws + 8 * MB);            // 6 MB
  short*          Wprj_t = (short*)(ws + 14 * MB);           // 2 MB
  unsigned short* Qb     = (unsigned short*)(ws + 16 * MB);  // 8 MB
  unsigned short* Kb     = (unsigned short*)(ws + 24 * MB);  // 8 MB
  unsigned short* Vtb    = (unsigned short*)(ws + 32 * MB);  // 8 MB
  unsigned short* ctx    = (unsigned short*)Xbf;

  prep<<<5120, 256, 0, stream>>>(x, (unsigned short*)Xbf,
                                 w_attn, (unsigned short*)Wqkv_t,
                                 w_proj, (unsigned short*)Wprj_t);
  gemm_qkv<<<dim3(32, 24), 256, 0, stream>>>(Xbf, Wqkv_t, b_attn, Qb, Kb, Vtb);
  flash_attn<<<dim3(32, 16), 256, 0, stream>>>((const short*)Qb, (const short*)Kb,
                                               (const short*)Vtb, mask, ctx);
  gemm_proj<<<dim3(64, 8), 256, 0, stream>>>((const short*)ctx, Wprj_t, b_proj, out);
}